// Round 1
// baseline (4075.017 us; speedup 1.0000x reference)
//
#include <hip/hip_runtime.h>
#include <stdint.h>
#include <stddef.h>

// Problem constants (fixed by the reference)
#define NN 50000    // nodes
#define NE 800000   // edges
#define NR 50       // relations
#define FIN 768
#define HD 256
#define NC 9

// ---- PRNG variant selection (decision tree across rounds) ----
// 0 = original threefry random-bits (pre-partitionable JAX)
// 1 = partitionable, bits = out0 ^ out1   <-- shipped round 1 (modern JAX default)
// 2 = partitionable, bits = out0
#define PRNG_MODE 1

// ---------------- Threefry-2x32-20 (JAX / Random123) ----------------
__host__ __device__ static inline void tf2x32(uint32_t k0, uint32_t k1,
                                              uint32_t x0, uint32_t x1,
                                              uint32_t& o0, uint32_t& o1) {
  uint32_t ks2 = k0 ^ k1 ^ 0x1BD11BDAu;
  x0 += k0; x1 += k1;
#define TF_R(r) { x0 += x1; x1 = (x1 << r) | (x1 >> (32 - r)); x1 ^= x0; }
  TF_R(13) TF_R(15) TF_R(26) TF_R(6)
  x0 += k1;  x1 += ks2 + 1u;
  TF_R(17) TF_R(29) TF_R(16) TF_R(24)
  x0 += ks2; x1 += k0 + 2u;
  TF_R(13) TF_R(15) TF_R(26) TF_R(6)
  x0 += k0;  x1 += k1 + 3u;
  TF_R(17) TF_R(29) TF_R(16) TF_R(24)
  x0 += k1;  x1 += ks2 + 4u;
  TF_R(13) TF_R(15) TF_R(26) TF_R(6)
  x0 += ks2; x1 += k0 + 5u;
#undef TF_R
  o0 = x0; o1 = x1;
}

// jax.random random_bits(key, 32, shape) for flat element i of a size-`total` array.
__device__ static inline uint32_t jax_bits32(uint32_t ka, uint32_t kb,
                                             uint32_t i, uint32_t half, int mode) {
  uint32_t o0, o1;
  if (mode == 0) {
    uint32_t j = (i < half) ? i : i - half;
    tf2x32(ka, kb, j, j + half, o0, o1);
    return (i < half) ? o0 : o1;
  } else {
    tf2x32(ka, kb, 0u, i, o0, o1);  // counter (hi=0, lo=i)
    return (mode == 1) ? (o0 ^ o1) : o0;
  }
}

// uniform[0,1) from bits, exactly as jax.random.uniform (f32)
__device__ static inline float jax_unif(uint32_t bits) {
  return __uint_as_float((bits >> 9) | 0x3f800000u) - 1.0f;
}

// ---------------- kernels ----------------

__global__ __launch_bounds__(256) void count_k(const int* __restrict__ ei,
                                               const int* __restrict__ et,
                                               unsigned* __restrict__ cnt) {
  int e = blockIdx.x * 256 + threadIdx.x;
  if (e >= NE) return;
  int dst = ei[NE + e];
  int t = et[e];
  atomicAdd(&cnt[(size_t)dst * NR + t], 1u);
}

// f32 SGEMM: C[M x Nw] = A[M x K] * B[K x Nw]; C has row stride ldc, base already
// offset to the target column block. BM=BN=128, BK=16, 256 threads, 8x8 microtile.
__global__ __launch_bounds__(256) void sgemm_k(const float* __restrict__ A,
                                               const float* __restrict__ B,
                                               float* __restrict__ C,
                                               int M, int K, int Nw, int ldc) {
  __shared__ float As[16][128 + 4];
  __shared__ float Bs[16][128];
  int bm = blockIdx.x * 128;
  int bn = blockIdx.y * 128;
  int tid = threadIdx.x;
  int tx = tid & 15;        // 16 col-groups
  int ty = tid >> 4;        // 16 row-groups
  float acc[8][8];
#pragma unroll
  for (int i = 0; i < 8; ++i)
#pragma unroll
    for (int j = 0; j < 8; ++j) acc[i][j] = 0.f;

  for (int k0 = 0; k0 < K; k0 += 16) {
    // A tile: 128 rows x 16 k
#pragma unroll
    for (int p = 0; p < 8; ++p) {
      int r = p * 16 + (tid >> 4);
      int kk = tid & 15;
      int gr = bm + r;
      As[kk][r] = (gr < M) ? A[(size_t)gr * K + k0 + kk] : 0.f;
    }
    // B tile: 16 k x 128 n
#pragma unroll
    for (int p = 0; p < 8; ++p) {
      int kk = p * 2 + (tid >> 7);
      int n = tid & 127;
      Bs[kk][n] = B[(size_t)(k0 + kk) * Nw + bn + n];
    }
    __syncthreads();
#pragma unroll
    for (int kk = 0; kk < 16; ++kk) {
      float a[8], b[8];
#pragma unroll
      for (int i = 0; i < 8; ++i) a[i] = As[kk][ty * 8 + i];
#pragma unroll
      for (int j = 0; j < 8; ++j) b[j] = Bs[kk][tx * 8 + j];
#pragma unroll
      for (int i = 0; i < 8; ++i)
#pragma unroll
        for (int j = 0; j < 8; ++j) acc[i][j] += a[i] * b[j];
    }
    __syncthreads();
  }
#pragma unroll
  for (int i = 0; i < 8; ++i) {
    int gr = bm + ty * 8 + i;
    if (gr < M) {
      float4* p = (float4*)&C[(size_t)gr * ldc + bn + tx * 8];
      p[0] = make_float4(acc[i][0], acc[i][1], acc[i][2], acc[i][3]);
      p[1] = make_float4(acc[i][4], acc[i][5], acc[i][6], acc[i][7]);
    }
  }
}

// one wave per edge: out1[dst, :] += (comp1[t]/cnt[dst,t]) * hx1[src, :]
// hxr1 layout: [NN][512]; cols 0..255 = hx1, cols 256..511 = x@root1 (accumulator)
__global__ __launch_bounds__(256) void scatter1_k(const int* __restrict__ ei,
                                                  const int* __restrict__ et,
                                                  const float* __restrict__ comp1,
                                                  const unsigned* __restrict__ cnt,
                                                  float* __restrict__ hxr1) {
  int gw = blockIdx.x * 4 + (threadIdx.x >> 6);
  int lane = threadIdx.x & 63;
  if (gw >= NE) return;
  int src = ei[gw];
  int dst = ei[NE + gw];
  int t = et[gw];
  float w = comp1[t] / (float)cnt[(size_t)dst * NR + t];
  const float4* hx = (const float4*)(hxr1 + (size_t)src * 512);
  float4 v = hx[lane];
  float* op = hxr1 + (size_t)dst * 512 + 256 + lane * 4;
  atomicAdd(op + 0, w * v.x);
  atomicAdd(op + 1, w * v.y);
  atomicAdd(op + 2, w * v.z);
  atomicAdd(op + 3, w * v.w);
}

// h1 = relu(dropout(out1 + bias1)); reads cols 256..511, writes cols 0..255
__global__ __launch_bounds__(256) void drelu1_k(float* __restrict__ hxr1,
                                                const float* __restrict__ bias1,
                                                uint32_t ka, uint32_t kb, int mode) {
  int i = blockIdx.x * 256 + threadIdx.x;
  const int total = NN * HD;
  if (i >= total) return;
  int n = i >> 8, c = i & 255;
  float v = hxr1[(size_t)n * 512 + 256 + c] + bias1[c];
  uint32_t bits = jax_bits32(ka, kb, (uint32_t)i, (uint32_t)(total / 2), mode);
  float r = (jax_unif(bits) < 0.6f) ? (v / 0.6f) : 0.0f;
  hxr1[(size_t)n * 512 + c] = fmaxf(r, 0.0f);
}

// layer-2 projections: hxr2[n, 0..8] = h1[n,:] @ basis2 ; hxr2[n, 9..17] = h1[n,:] @ root2
__global__ __launch_bounds__(256) void gemm2_k(const float* __restrict__ h1base,
                                               const float* __restrict__ basis2,
                                               const float* __restrict__ root2,
                                               float* __restrict__ hxr2) {
  __shared__ float W[256][18];
  int tid = threadIdx.x;
  for (int p = tid; p < 256 * 18; p += 256) {
    int k = p / 18, c = p % 18;
    W[k][c] = (c < 9) ? basis2[k * 9 + c] : root2[k * 9 + (c - 9)];
  }
  __syncthreads();
  int wave = tid >> 6, lane = tid & 63;
  int row = blockIdx.x * 4 + wave;
  if (row >= NN) return;
  const float* h1 = h1base + (size_t)row * 512;
  float acc[18];
#pragma unroll
  for (int c = 0; c < 18; ++c) acc[c] = 0.f;
#pragma unroll
  for (int q = 0; q < 4; ++q) {
    float a = h1[lane + q * 64];
#pragma unroll
    for (int c = 0; c < 18; ++c) acc[c] += a * W[lane + q * 64][c];
  }
#pragma unroll
  for (int c = 0; c < 18; ++c) {
    float v = acc[c];
#pragma unroll
    for (int off = 32; off > 0; off >>= 1) v += __shfl_down(v, off, 64);
    if (lane == 0) hxr2[(size_t)row * 18 + c] = v;
  }
}

// out2[dst, :] += (comp2[t]/cnt[dst,t]) * hx2[src, :]; hxr2 cols 9..17 accumulate
__global__ __launch_bounds__(256) void scatter2_k(const int* __restrict__ ei,
                                                  const int* __restrict__ et,
                                                  const float* __restrict__ comp2,
                                                  const unsigned* __restrict__ cnt,
                                                  float* __restrict__ hxr2) {
  int e = blockIdx.x * 256 + threadIdx.x;
  if (e >= NE) return;
  int src = ei[e];
  int dst = ei[NE + e];
  int t = et[e];
  float w = comp2[t] / (float)cnt[(size_t)dst * NR + t];
  const float* hx = hxr2 + (size_t)src * 18;
  float* op = hxr2 + (size_t)dst * 18 + 9;
#pragma unroll
  for (int c = 0; c < 9; ++c) atomicAdd(op + c, w * hx[c]);
}

__global__ __launch_bounds__(256) void final_k(const float* __restrict__ hxr2,
                                               const float* __restrict__ bias2,
                                               float* __restrict__ out,
                                               uint32_t ka, uint32_t kb, int mode) {
  int i = blockIdx.x * 256 + threadIdx.x;
  const int total = NN * NC;
  if (i >= total) return;
  int n = i / 9, c = i - n * 9;
  float v = hxr2[(size_t)n * 18 + 9 + c] + bias2[c];
  uint32_t bits = jax_bits32(ka, kb, (uint32_t)i, (uint32_t)(total / 2), mode);
  float r = (jax_unif(bits) < 0.6f) ? (v / 0.6f) : 0.0f;
  out[i] = fmaxf(r, 0.0f);
}

// ---------------- launch ----------------
extern "C" void kernel_launch(void* const* d_in, const int* in_sizes, int n_in,
                              void* d_out, int out_size, void* d_ws, size_t ws_size,
                              hipStream_t stream) {
  (void)in_sizes; (void)n_in; (void)out_size; (void)ws_size;
  const float* x      = (const float*)d_in[0];
  const int*   ei     = (const int*)d_in[1];
  const int*   et     = (const int*)d_in[2];
  // d_in[3] = edge_distance (unused by the reference)
  const float* basis1 = (const float*)d_in[4];
  const float* comp1  = (const float*)d_in[5];
  const float* root1  = (const float*)d_in[6];
  const float* bias1  = (const float*)d_in[7];
  const float* basis2 = (const float*)d_in[8];
  const float* comp2  = (const float*)d_in[9];
  const float* root2  = (const float*)d_in[10];
  const float* bias2  = (const float*)d_in[11];
  float* out = (float*)d_out;

  char* ws = (char*)d_ws;
  unsigned* cnt = (unsigned*)ws;                         // 10,000,000 B
  float* hxr1   = (float*)(ws + 10000128);               // [NN][512] f32 = 102,400,000 B
  float* hxr2   = (float*)(ws + 10000128 + 102400000);   // [NN][18] f32 = 3,600,000 B

  // Derive k1, k2 = jax.random.split(jax.random.key(42)) on host, per PRNG mode.
  uint32_t k1a, k1b, k2a, k2b;
#if PRNG_MODE == 0
  {
    uint32_t a0, a1, b0, b1;
    tf2x32(0u, 42u, 0u, 2u, a0, a1);  // block (counts[0], counts[2])
    tf2x32(0u, 42u, 1u, 3u, b0, b1);  // block (counts[1], counts[3])
    k1a = a0; k1b = b0;               // keys[0] = (out0[0], out0[1])
    k2a = a1; k2b = b1;               // keys[1] = (out1[0], out1[1])
  }
#else
  tf2x32(0u, 42u, 0u, 0u, k1a, k1b);  // fold-like split: key_j = E(key, (0, j))
  tf2x32(0u, 42u, 0u, 1u, k2a, k2b);
#endif

  hipMemsetAsync(cnt, 0, (size_t)NN * NR * 4, stream);
  count_k<<<(NE + 255) / 256, 256, 0, stream>>>(ei, et, cnt);

  dim3 g1((NN + 127) / 128, 2);
  sgemm_k<<<g1, 256, 0, stream>>>(x, basis1, hxr1 + 0,   NN, FIN, HD, 512);
  sgemm_k<<<g1, 256, 0, stream>>>(x, root1,  hxr1 + 256, NN, FIN, HD, 512);

  scatter1_k<<<NE / 4, 256, 0, stream>>>(ei, et, comp1, cnt, hxr1);

  drelu1_k<<<(NN * HD + 255) / 256, 256, 0, stream>>>(hxr1, bias1, k1a, k1b, PRNG_MODE);

  gemm2_k<<<(NN + 3) / 4, 256, 0, stream>>>(hxr1, basis2, root2, hxr2);

  scatter2_k<<<(NE + 255) / 256, 256, 0, stream>>>(ei, et, comp2, cnt, hxr2);

  final_k<<<(NN * NC + 255) / 256, 256, 0, stream>>>(hxr2, bias2, out, k1a == k1a ? k2a : k2a, k2b, PRNG_MODE);
}

// Round 2
// 1241.329 us; speedup vs baseline: 3.2828x; 3.2828x over previous
//
#include <hip/hip_runtime.h>
#include <stdint.h>
#include <stddef.h>

// Problem constants (fixed by the reference)
#define NN 50000    // nodes
#define NE 800000   // edges
#define NR 50       // relations
#define FIN 768
#define HD 256
#define NC 9

// PRNG mode 1 (partitionable threefry, bits = out0^out1) — verified round 1.

// ---------------- Threefry-2x32-20 (JAX / Random123) ----------------
__host__ __device__ static inline void tf2x32(uint32_t k0, uint32_t k1,
                                              uint32_t x0, uint32_t x1,
                                              uint32_t& o0, uint32_t& o1) {
  uint32_t ks2 = k0 ^ k1 ^ 0x1BD11BDAu;
  x0 += k0; x1 += k1;
#define TF_R(r) { x0 += x1; x1 = (x1 << r) | (x1 >> (32 - r)); x1 ^= x0; }
  TF_R(13) TF_R(15) TF_R(26) TF_R(6)
  x0 += k1;  x1 += ks2 + 1u;
  TF_R(17) TF_R(29) TF_R(16) TF_R(24)
  x0 += ks2; x1 += k0 + 2u;
  TF_R(13) TF_R(15) TF_R(26) TF_R(6)
  x0 += k0;  x1 += k1 + 3u;
  TF_R(17) TF_R(29) TF_R(16) TF_R(24)
  x0 += k1;  x1 += ks2 + 4u;
  TF_R(13) TF_R(15) TF_R(26) TF_R(6)
  x0 += ks2; x1 += k0 + 5u;
#undef TF_R
  o0 = x0; o1 = x1;
}

__device__ static inline uint32_t jax_bits32(uint32_t ka, uint32_t kb, uint32_t i) {
  uint32_t o0, o1;
  tf2x32(ka, kb, 0u, i, o0, o1);  // counter (hi=0, lo=i)
  return o0 ^ o1;
}

__device__ static inline float jax_unif(uint32_t bits) {
  return __uint_as_float((bits >> 9) | 0x3f800000u) - 1.0f;
}

// dropout(p=0.4)+relu on value v at flat index i
__device__ static inline float drelu(float v, uint32_t ka, uint32_t kb, uint32_t i) {
  uint32_t bits = jax_bits32(ka, kb, i);
  float r = (jax_unif(bits) < 0.6f) ? (v * (1.0f / 0.6f)) : 0.0f;
  return fmaxf(r, 0.0f);
}

// ---------------- kernels ----------------

// cnt[dst*NR+t]++ and deg[dst]++
__global__ __launch_bounds__(256) void count_k(const int* __restrict__ ei,
                                               const int* __restrict__ et,
                                               unsigned* __restrict__ cnt,
                                               unsigned* __restrict__ deg) {
  int e = blockIdx.x * 256 + threadIdx.x;
  if (e >= NE) return;
  int dst = ei[NE + e];
  int t = et[e];
  atomicAdd(&cnt[(size_t)dst * NR + t], 1u);
  atomicAdd(&deg[dst], 1u);
}

// single-block exclusive scan of deg[NN] -> rowstart[NN+1]
__global__ __launch_bounds__(256) void scan_k(const unsigned* __restrict__ deg,
                                              int* __restrict__ rowstart) {
  __shared__ int part[256];
  const int CH = (NN + 255) / 256;  // 196
  int t = threadIdx.x;
  int lo = t * CH, hi = min(lo + CH, NN);
  int s = 0;
  for (int i = lo; i < hi; ++i) s += (int)deg[i];
  part[t] = s;
  __syncthreads();
  for (int off = 1; off < 256; off <<= 1) {
    int v = 0;
    if (t >= off) v = part[t - off];
    __syncthreads();
    part[t] += v;
    __syncthreads();
  }
  int run = (t == 0) ? 0 : part[t - 1];
  for (int i = lo; i < hi; ++i) { rowstart[i] = run; run += (int)deg[i]; }
  if (t == 255) rowstart[NN] = run;  // == NE
}

// fill CSR slots: elist[slot]=src, w1l/w2l[slot]=comp/cnt weights
__global__ __launch_bounds__(256) void fill_k(const int* __restrict__ ei,
                                              const int* __restrict__ et,
                                              const float* __restrict__ comp1,
                                              const float* __restrict__ comp2,
                                              const unsigned* __restrict__ cnt,
                                              const int* __restrict__ rowstart,
                                              unsigned* __restrict__ cursor,
                                              int* __restrict__ elist,
                                              float* __restrict__ w1l,
                                              float* __restrict__ w2l) {
  int e = blockIdx.x * 256 + threadIdx.x;
  if (e >= NE) return;
  int src = ei[e];
  int dst = ei[NE + e];
  int t = et[e];
  unsigned pos = atomicAdd(&cursor[dst], 1u);
  int slot = rowstart[dst] + (int)pos;
  float ic = 1.0f / (float)cnt[(size_t)dst * NR + t];
  elist[slot] = src;
  w1l[slot] = comp1[t] * ic;
  w2l[slot] = comp2[t] * ic;
}

// f32 SGEMM: C[M x Nw] = A[M x K] * B[K x Nw], row stride ldc.
__global__ __launch_bounds__(256) void sgemm_k(const float* __restrict__ A,
                                               const float* __restrict__ B,
                                               float* __restrict__ C,
                                               int M, int K, int Nw, int ldc) {
  __shared__ float As[16][128 + 4];
  __shared__ float Bs[16][128];
  int bm = blockIdx.x * 128;
  int bn = blockIdx.y * 128;
  int tid = threadIdx.x;
  int tx = tid & 15;
  int ty = tid >> 4;
  float acc[8][8];
#pragma unroll
  for (int i = 0; i < 8; ++i)
#pragma unroll
    for (int j = 0; j < 8; ++j) acc[i][j] = 0.f;

  for (int k0 = 0; k0 < K; k0 += 16) {
#pragma unroll
    for (int p = 0; p < 8; ++p) {
      int r = p * 16 + (tid >> 4);
      int kk = tid & 15;
      int gr = bm + r;
      As[kk][r] = (gr < M) ? A[(size_t)gr * K + k0 + kk] : 0.f;
    }
#pragma unroll
    for (int p = 0; p < 8; ++p) {
      int kk = p * 2 + (tid >> 7);
      int n = tid & 127;
      Bs[kk][n] = B[(size_t)(k0 + kk) * Nw + bn + n];
    }
    __syncthreads();
#pragma unroll
    for (int kk = 0; kk < 16; ++kk) {
      float a[8], b[8];
#pragma unroll
      for (int i = 0; i < 8; ++i) a[i] = As[kk][ty * 8 + i];
#pragma unroll
      for (int j = 0; j < 8; ++j) b[j] = Bs[kk][tx * 8 + j];
#pragma unroll
      for (int i = 0; i < 8; ++i)
#pragma unroll
        for (int j = 0; j < 8; ++j) acc[i][j] += a[i] * b[j];
    }
    __syncthreads();
  }
#pragma unroll
  for (int i = 0; i < 8; ++i) {
    int gr = bm + ty * 8 + i;
    if (gr < M) {
      float4* p = (float4*)&C[(size_t)gr * ldc + bn + tx * 8];
      p[0] = make_float4(acc[i][0], acc[i][1], acc[i][2], acc[i][3]);
      p[1] = make_float4(acc[i][4], acc[i][5], acc[i][6], acc[i][7]);
    }
  }
}

// one wave per dst node: agg = sum w1*hx1[src]; h1 = relu(dropout(agg + xr + b1))
// writes h1 in place over xr (own row only).
__global__ __launch_bounds__(256) void gather1_k(const int* __restrict__ rowstart,
                                                 const int* __restrict__ elist,
                                                 const float* __restrict__ w1l,
                                                 const float* __restrict__ hx1,
                                                 float* __restrict__ xr,
                                                 const float* __restrict__ bias1,
                                                 uint32_t ka, uint32_t kb) {
  int node = blockIdx.x * 4 + (threadIdx.x >> 6);
  int lane = threadIdx.x & 63;
  if (node >= NN) return;
  int rs = rowstart[node], re = rowstart[node + 1];
  float4 acc = make_float4(0.f, 0.f, 0.f, 0.f);
  for (int j = rs; j < re; ++j) {
    int src = elist[j];      // wave-uniform broadcast
    float w = w1l[j];
    float4 v = *(const float4*)(hx1 + (size_t)src * HD + lane * 4);
    acc.x += w * v.x; acc.y += w * v.y; acc.z += w * v.z; acc.w += w * v.w;
  }
  float* xrow = xr + (size_t)node * HD + lane * 4;
  float4 r = *(const float4*)xrow;
  float4 b = *(const float4*)(bias1 + lane * 4);
  uint32_t base = (uint32_t)(node * HD + lane * 4);
  float4 o;
  o.x = drelu(acc.x + r.x + b.x, ka, kb, base + 0);
  o.y = drelu(acc.y + r.y + b.y, ka, kb, base + 1);
  o.z = drelu(acc.z + r.z + b.z, ka, kb, base + 2);
  o.w = drelu(acc.w + r.w + b.w, ka, kb, base + 3);
  *(float4*)xrow = o;
}

// layer-2 projections: hxr2[n, 0..8] = h1[n,:]@basis2 ; hxr2[n, 9..17] = h1[n,:]@root2
__global__ __launch_bounds__(256) void gemm2_k(const float* __restrict__ h1base,
                                               const float* __restrict__ basis2,
                                               const float* __restrict__ root2,
                                               float* __restrict__ hxr2) {
  __shared__ float W[256][18];
  int tid = threadIdx.x;
  for (int p = tid; p < 256 * 18; p += 256) {
    int k = p / 18, c = p % 18;
    W[k][c] = (c < 9) ? basis2[k * 9 + c] : root2[k * 9 + (c - 9)];
  }
  __syncthreads();
  int wave = tid >> 6, lane = tid & 63;
  int row = blockIdx.x * 4 + wave;
  if (row >= NN) return;
  const float* h1 = h1base + (size_t)row * HD;
  float acc[18];
#pragma unroll
  for (int c = 0; c < 18; ++c) acc[c] = 0.f;
#pragma unroll
  for (int q = 0; q < 4; ++q) {
    float a = h1[lane + q * 64];
#pragma unroll
    for (int c = 0; c < 18; ++c) acc[c] += a * W[lane + q * 64][c];
  }
#pragma unroll
  for (int c = 0; c < 18; ++c) {
    float v = acc[c];
#pragma unroll
    for (int off = 32; off > 0; off >>= 1) v += __shfl_down(v, off, 64);
    if (lane == 0) hxr2[(size_t)row * 18 + c] = v;
  }
}

// one thread per dst node: out = relu(dropout(sum w2*hx2[src] + xr2 + b2))
__global__ __launch_bounds__(256) void gather2_k(const int* __restrict__ rowstart,
                                                 const int* __restrict__ elist,
                                                 const float* __restrict__ w2l,
                                                 const float* __restrict__ hxr2,
                                                 const float* __restrict__ bias2,
                                                 float* __restrict__ out,
                                                 uint32_t ka, uint32_t kb) {
  int n = blockIdx.x * 256 + threadIdx.x;
  if (n >= NN) return;
  int rs = rowstart[n], re = rowstart[n + 1];
  float acc[9];
#pragma unroll
  for (int c = 0; c < 9; ++c) acc[c] = 0.f;
  for (int j = rs; j < re; ++j) {
    int src = elist[j];
    float w = w2l[j];
    const float* hp = hxr2 + (size_t)src * 18;
#pragma unroll
    for (int c = 0; c < 9; ++c) acc[c] += w * hp[c];
  }
  const float* xp = hxr2 + (size_t)n * 18 + 9;
#pragma unroll
  for (int c = 0; c < 9; ++c) {
    float v = acc[c] + xp[c] + bias2[c];
    out[n * 9 + c] = drelu(v, ka, kb, (uint32_t)(n * 9 + c));
  }
}

// ---------------- launch ----------------
extern "C" void kernel_launch(void* const* d_in, const int* in_sizes, int n_in,
                              void* d_out, int out_size, void* d_ws, size_t ws_size,
                              hipStream_t stream) {
  (void)in_sizes; (void)n_in; (void)out_size; (void)ws_size;
  const float* x      = (const float*)d_in[0];
  const int*   ei     = (const int*)d_in[1];
  const int*   et     = (const int*)d_in[2];
  const float* basis1 = (const float*)d_in[4];
  const float* comp1  = (const float*)d_in[5];
  const float* root1  = (const float*)d_in[6];
  const float* bias1  = (const float*)d_in[7];
  const float* basis2 = (const float*)d_in[8];
  const float* comp2  = (const float*)d_in[9];
  const float* root2  = (const float*)d_in[10];
  const float* bias2  = (const float*)d_in[11];
  float* out = (float*)d_out;

  // workspace layout (bytes)
  char* ws = (char*)d_ws;
  unsigned* cnt    = (unsigned*)(ws);                        // 10,000,128
  unsigned* deg    = (unsigned*)(ws + 10000128);             //    200,064
  unsigned* cursor = (unsigned*)(ws + 10200192);             //    200,064
  int* rowstart    = (int*)     (ws + 10400256);             //    200,128
  int* elist       = (int*)     (ws + 10600384);             //  3,200,000
  float* w1l       = (float*)   (ws + 13800384);             //  3,200,000
  float* w2l       = (float*)   (ws + 17000384);             //  3,200,000
  float* hx1       = (float*)   (ws + 20200384);             // 51,200,000
  float* xr        = (float*)   (ws + 71400384);             // 51,200,000
  float* hxr2      = (float*)   (ws);                        // overlays cnt (dead after fill_k)

  // k1, k2 = jax.random.split(jax.random.key(42)), partitionable scheme
  uint32_t k1a, k1b, k2a, k2b;
  tf2x32(0u, 42u, 0u, 0u, k1a, k1b);
  tf2x32(0u, 42u, 0u, 1u, k2a, k2b);

  // zero cnt + deg + cursor in one shot (contiguous)
  hipMemsetAsync(ws, 0, 10400256, stream);

  count_k<<<(NE + 255) / 256, 256, 0, stream>>>(ei, et, cnt, deg);
  scan_k<<<1, 256, 0, stream>>>(deg, rowstart);
  fill_k<<<(NE + 255) / 256, 256, 0, stream>>>(ei, et, comp1, comp2, cnt, rowstart,
                                               cursor, elist, w1l, w2l);

  dim3 g1((NN + 127) / 128, 2);
  sgemm_k<<<g1, 256, 0, stream>>>(x, basis1, hx1, NN, FIN, HD, HD);
  sgemm_k<<<g1, 256, 0, stream>>>(x, root1,  xr,  NN, FIN, HD, HD);

  gather1_k<<<(NN + 3) / 4, 256, 0, stream>>>(rowstart, elist, w1l, hx1, xr, bias1,
                                              k1a, k1b);

  gemm2_k<<<(NN + 3) / 4, 256, 0, stream>>>(xr, basis2, root2, hxr2);

  gather2_k<<<(NN + 255) / 256, 256, 0, stream>>>(rowstart, elist, w2l, hxr2, bias2,
                                                  out, k2a, k2b);
}

// Round 3
// 554.296 us; speedup vs baseline: 7.3517x; 2.2395x over previous
//
#include <hip/hip_runtime.h>
#include <stdint.h>
#include <stddef.h>

// Problem constants (fixed by the reference)
#define NN 50000    // nodes
#define NE 800000   // edges
#define NR 50       // relations
#define FIN 768
#define HD 256
#define NC 9

typedef __bf16 bf16x8 __attribute__((ext_vector_type(8)));
typedef float f32x4 __attribute__((ext_vector_type(4)));
typedef unsigned short ushort_t;

// ---------------- Threefry-2x32-20 (JAX / Random123, partitionable) ----------------
__host__ __device__ static inline void tf2x32(uint32_t k0, uint32_t k1,
                                              uint32_t x0, uint32_t x1,
                                              uint32_t& o0, uint32_t& o1) {
  uint32_t ks2 = k0 ^ k1 ^ 0x1BD11BDAu;
  x0 += k0; x1 += k1;
#define TF_R(r) { x0 += x1; x1 = (x1 << r) | (x1 >> (32 - r)); x1 ^= x0; }
  TF_R(13) TF_R(15) TF_R(26) TF_R(6)
  x0 += k1;  x1 += ks2 + 1u;
  TF_R(17) TF_R(29) TF_R(16) TF_R(24)
  x0 += ks2; x1 += k0 + 2u;
  TF_R(13) TF_R(15) TF_R(26) TF_R(6)
  x0 += k0;  x1 += k1 + 3u;
  TF_R(17) TF_R(29) TF_R(16) TF_R(24)
  x0 += k1;  x1 += ks2 + 4u;
  TF_R(13) TF_R(15) TF_R(26) TF_R(6)
  x0 += ks2; x1 += k0 + 5u;
#undef TF_R
  o0 = x0; o1 = x1;
}

__device__ static inline float jax_unif(uint32_t ka, uint32_t kb, uint32_t i) {
  uint32_t o0, o1;
  tf2x32(ka, kb, 0u, i, o0, o1);
  uint32_t bits = o0 ^ o1;
  return __uint_as_float((bits >> 9) | 0x3f800000u) - 1.0f;
}

// dropout(p=0.4)+relu on value v at flat index i
__device__ static inline float drelu(float v, uint32_t ka, uint32_t kb, uint32_t i) {
  float r = (jax_unif(ka, kb, i) < 0.6f) ? (v * (1.0f / 0.6f)) : 0.0f;
  return fmaxf(r, 0.0f);
}

// f32 -> bf16 (round half up), packed pair
__device__ static inline uint32_t pk2(float lo, float hi) {
  uint32_t a = (__float_as_uint(lo) + 0x8000u) >> 16;
  uint32_t b = (__float_as_uint(hi) + 0x8000u) & 0xFFFF0000u;
  return a | b;
}

// LDS tile byte offset for (row r, 16B-segment s), XOR-swizzled (involution)
__device__ static inline int swz(int r, int s) {
  return r * 64 + ((s ^ ((r >> 1) & 3)) << 4);
}

#define GLDS16(gp, lp) __builtin_amdgcn_global_load_lds(                        \
    (const __attribute__((address_space(1))) void*)(gp),                        \
    (__attribute__((address_space(3))) void*)(lp), 16, 0, 0)

// ---------------- graph prep ----------------

__global__ __launch_bounds__(256) void count_k(const int* __restrict__ ei,
                                               const int* __restrict__ et,
                                               unsigned* __restrict__ cnt,
                                               unsigned* __restrict__ deg) {
  int e = blockIdx.x * 256 + threadIdx.x;
  if (e >= NE) return;
  int dst = ei[NE + e];
  int t = et[e];
  atomicAdd(&cnt[(size_t)dst * NR + t], 1u);
  atomicAdd(&deg[dst], 1u);
}

__global__ __launch_bounds__(256) void scan_k(const unsigned* __restrict__ deg,
                                              int* __restrict__ rowstart) {
  __shared__ int part[256];
  const int CH = (NN + 255) / 256;
  int t = threadIdx.x;
  int lo = t * CH, hi = min(lo + CH, NN);
  int s = 0;
  for (int i = lo; i < hi; ++i) s += (int)deg[i];
  part[t] = s;
  __syncthreads();
  for (int off = 1; off < 256; off <<= 1) {
    int v = 0;
    if (t >= off) v = part[t - off];
    __syncthreads();
    part[t] += v;
    __syncthreads();
  }
  int run = (t == 0) ? 0 : part[t - 1];
  for (int i = lo; i < hi; ++i) { rowstart[i] = run; run += (int)deg[i]; }
  if (t == 255) rowstart[NN] = run;
}

// CSR slots: epack = src | (t<<16) (src<65536, t<64), icl = 1/cnt
__global__ __launch_bounds__(256) void fill_k(const int* __restrict__ ei,
                                              const int* __restrict__ et,
                                              const unsigned* __restrict__ cnt,
                                              const int* __restrict__ rowstart,
                                              unsigned* __restrict__ cursor,
                                              uint32_t* __restrict__ epack,
                                              float* __restrict__ icl) {
  int e = blockIdx.x * 256 + threadIdx.x;
  if (e >= NE) return;
  int src = ei[e];
  int dst = ei[NE + e];
  int t = et[e];
  unsigned pos = atomicAdd(&cursor[dst], 1u);
  int slot = rowstart[dst] + (int)pos;
  epack[slot] = (uint32_t)src | ((uint32_t)t << 16);
  icl[slot] = 1.0f / (float)cnt[(size_t)dst * NR + t];
}

// Bcat[n][k] bf16, n in [0,512): n<256 -> basis1[0][k][n], else root1[k][n-256]
__global__ __launch_bounds__(256) void bcat_k(const float* __restrict__ basis1,
                                              const float* __restrict__ root1,
                                              ushort_t* __restrict__ Bcat) {
  int i = blockIdx.x * 256 + threadIdx.x;
  if (i >= 512 * FIN) return;
  int n = i / FIN, k = i - n * FIN;
  float v = (n < HD) ? basis1[k * HD + n] : root1[k * HD + (n - HD)];
  Bcat[i] = (ushort_t)((__float_as_uint(v) + 0x8000u) >> 16);
}

// ---------------- fused layer-1 GEMM: hxr[M][512] = x[M][768] @ [basis1|root1] ----------------
// bf16 MFMA 16x16x32, 128x128 tile, BK=32, 4 waves (2x2), 4x4 frags/wave.
// B staged via global_load_lds (pre-swizzled source), A reg-staged + f32->bf16 cvt.
__global__ __launch_bounds__(256) void mfma_gemm_k(const float* __restrict__ A,
                                                   const ushort_t* __restrict__ Bc,
                                                   float* __restrict__ C, int M) {
  __shared__ alignas(16) unsigned char ldsA[8192];
  __shared__ alignas(16) unsigned char ldsB[8192];
  const int K = FIN;
  int bm = blockIdx.x * 128;
  int bn = blockIdx.y * 128;
  int t = threadIdx.x;
  int lane = t & 63, w = t >> 6;
  int wm = w >> 1, wn = w & 1;
  int fr = lane & 15, fs = lane >> 4;

  f32x4 acc[4][4];
#pragma unroll
  for (int m = 0; m < 4; ++m)
#pragma unroll
    for (int n = 0; n < 4; ++n) acc[m][n] = (f32x4){0.f, 0.f, 0.f, 0.f};

  // fragment read offsets (constant across K-steps)
  int aoff[4], boff[4];
#pragma unroll
  for (int m = 0; m < 4; ++m) aoff[m] = swz(wm * 64 + m * 16 + fr, fs);
#pragma unroll
  for (int n = 0; n < 4; ++n) boff[n] = swz(wn * 64 + n * 16 + fr, fs);

  // A staging addressing: thread -> (row = t>>1, 16-float half = t&1)
  int rA = t >> 1, half = t & 1;
  const float4* gA =
      (const float4*)(A + (size_t)min(bm + rA, M - 1) * K + half * 16);

  float4 f0, f1, f2, f3;
  {
    const float4* p = gA;
    f0 = p[0]; f1 = p[1]; f2 = p[2]; f3 = p[3];
  }

  for (int k0 = 0; k0 < K; k0 += 32) {
    __syncthreads();  // previous compute done; LDS free; A regs arrived
    // B stage: 2 x 16B chunks per thread, pre-swizzled global source
#pragma unroll
    for (int q = 0; q < 2; ++q) {
      int c = q * 256 + t;
      int r = c >> 2, sp = c & 3;
      int s = sp ^ ((r >> 1) & 3);
      GLDS16(Bc + (size_t)(bn + r) * K + k0 + s * 8,
             ldsB + q * 4096 + w * 1024);
    }
    // A: cvt + swizzled ds_write (two 16B chunks)
    uint4 c0, c1;
    c0.x = pk2(f0.x, f0.y); c0.y = pk2(f0.z, f0.w);
    c0.z = pk2(f1.x, f1.y); c0.w = pk2(f1.z, f1.w);
    c1.x = pk2(f2.x, f2.y); c1.y = pk2(f2.z, f2.w);
    c1.z = pk2(f3.x, f3.y); c1.w = pk2(f3.z, f3.w);
    *(uint4*)(ldsA + swz(rA, half * 2)) = c0;
    *(uint4*)(ldsA + swz(rA, half * 2 + 1)) = c1;
    __syncthreads();  // drains vmcnt (B in LDS) + lgkm (A writes)
    // issue next step's A loads early; latency hides under MFMAs
    if (k0 + 32 < K) {
      const float4* p = gA + ((k0 + 32) >> 2);
      f0 = p[0]; f1 = p[1]; f2 = p[2]; f3 = p[3];
    }
    bf16x8 af[4], bfr[4];
#pragma unroll
    for (int m = 0; m < 4; ++m) af[m] = *(const bf16x8*)(ldsA + aoff[m]);
#pragma unroll
    for (int n = 0; n < 4; ++n) bfr[n] = *(const bf16x8*)(ldsB + boff[n]);
#pragma unroll
    for (int m = 0; m < 4; ++m)
#pragma unroll
      for (int n = 0; n < 4; ++n)
        acc[m][n] = __builtin_amdgcn_mfma_f32_16x16x32_bf16(af[m], bfr[n],
                                                            acc[m][n], 0, 0, 0);
  }

  // epilogue: C/D layout col = lane&15, row = (lane>>4)*4 + reg  [m89-verified]
#pragma unroll
  for (int m = 0; m < 4; ++m) {
    int rbase = bm + wm * 64 + m * 16 + fs * 4;
#pragma unroll
    for (int r4 = 0; r4 < 4; ++r4) {
      int row = rbase + r4;
      if (row < M) {
        float* crow = C + (size_t)row * 512 + bn + wn * 64 + fr;
#pragma unroll
        for (int n = 0; n < 4; ++n) crow[n * 16] = acc[m][n][r4];
      }
    }
  }
}

// ---------------- aggregation / epilogues ----------------

// one wave per dst node over hxr[N][512] (cols 0..255 = hx, 256..511 = xr);
// writes h1 over xr half.
__global__ __launch_bounds__(256) void gather1_k(const int* __restrict__ rowstart,
                                                 const uint32_t* __restrict__ epack,
                                                 const float* __restrict__ icl,
                                                 const float* __restrict__ comp1,
                                                 float* __restrict__ hxr,
                                                 const float* __restrict__ bias1,
                                                 uint32_t ka, uint32_t kb) {
  int node = blockIdx.x * 4 + (threadIdx.x >> 6);
  int lane = threadIdx.x & 63;
  if (node >= NN) return;
  int rs = rowstart[node], re = rowstart[node + 1];
  float4 acc = make_float4(0.f, 0.f, 0.f, 0.f);
  for (int j = rs; j < re; ++j) {
    uint32_t e = epack[j];
    int src = (int)(e & 0xFFFFu);
    float w = comp1[e >> 16] * icl[j];
    float4 v = *(const float4*)(hxr + (size_t)src * 512 + lane * 4);
    acc.x += w * v.x; acc.y += w * v.y; acc.z += w * v.z; acc.w += w * v.w;
  }
  float* xrow = hxr + (size_t)node * 512 + 256 + lane * 4;
  float4 r = *(const float4*)xrow;
  float4 b = *(const float4*)(bias1 + lane * 4);
  uint32_t base = (uint32_t)(node * HD + lane * 4);
  float4 o;
  o.x = drelu(acc.x + r.x + b.x, ka, kb, base + 0);
  o.y = drelu(acc.y + r.y + b.y, ka, kb, base + 1);
  o.z = drelu(acc.z + r.z + b.z, ka, kb, base + 2);
  o.w = drelu(acc.w + r.w + b.w, ka, kb, base + 3);
  *(float4*)xrow = o;
}

// layer-2 projections: hxr2[n,0..8] = h1[n,:]@basis2 ; hxr2[n,9..17] = h1[n,:]@root2
// h1 rows live at h1base + row*512 (stride 512)
__global__ __launch_bounds__(256) void gemm2_k(const float* __restrict__ h1base,
                                               const float* __restrict__ basis2,
                                               const float* __restrict__ root2,
                                               float* __restrict__ hxr2) {
  __shared__ float W[256][18];
  int tid = threadIdx.x;
  for (int p = tid; p < 256 * 18; p += 256) {
    int k = p / 18, c = p % 18;
    W[k][c] = (c < 9) ? basis2[k * 9 + c] : root2[k * 9 + (c - 9)];
  }
  __syncthreads();
  int wave = tid >> 6, lane = tid & 63;
  int row = blockIdx.x * 4 + wave;
  if (row >= NN) return;
  const float* h1 = h1base + (size_t)row * 512;
  float acc[18];
#pragma unroll
  for (int c = 0; c < 18; ++c) acc[c] = 0.f;
#pragma unroll
  for (int q = 0; q < 4; ++q) {
    float a = h1[lane + q * 64];
#pragma unroll
    for (int c = 0; c < 18; ++c) acc[c] += a * W[lane + q * 64][c];
  }
#pragma unroll
  for (int c = 0; c < 18; ++c) {
    float v = acc[c];
#pragma unroll
    for (int off = 32; off > 0; off >>= 1) v += __shfl_down(v, off, 64);
    if (lane == 0) hxr2[(size_t)row * 18 + c] = v;
  }
}

// one thread per dst node: out = relu(dropout(sum w2*hx2[src] + xr2 + b2))
__global__ __launch_bounds__(256) void gather2_k(const int* __restrict__ rowstart,
                                                 const uint32_t* __restrict__ epack,
                                                 const float* __restrict__ icl,
                                                 const float* __restrict__ comp2,
                                                 const float* __restrict__ hxr2,
                                                 const float* __restrict__ bias2,
                                                 float* __restrict__ out,
                                                 uint32_t ka, uint32_t kb) {
  int n = blockIdx.x * 256 + threadIdx.x;
  if (n >= NN) return;
  int rs = rowstart[n], re = rowstart[n + 1];
  float acc[9];
#pragma unroll
  for (int c = 0; c < 9; ++c) acc[c] = 0.f;
  for (int j = rs; j < re; ++j) {
    uint32_t e = epack[j];
    int src = (int)(e & 0xFFFFu);
    float w = comp2[e >> 16] * icl[j];
    const float* hp = hxr2 + (size_t)src * 18;
#pragma unroll
    for (int c = 0; c < 9; ++c) acc[c] += w * hp[c];
  }
  const float* xp = hxr2 + (size_t)n * 18 + 9;
#pragma unroll
  for (int c = 0; c < 9; ++c) {
    float v = acc[c] + xp[c] + bias2[c];
    out[n * 9 + c] = drelu(v, ka, kb, (uint32_t)(n * 9 + c));
  }
}

// ---------------- launch ----------------
extern "C" void kernel_launch(void* const* d_in, const int* in_sizes, int n_in,
                              void* d_out, int out_size, void* d_ws, size_t ws_size,
                              hipStream_t stream) {
  (void)in_sizes; (void)n_in; (void)out_size; (void)ws_size;
  const float* x      = (const float*)d_in[0];
  const int*   ei     = (const int*)d_in[1];
  const int*   et     = (const int*)d_in[2];
  const float* basis1 = (const float*)d_in[4];
  const float* comp1  = (const float*)d_in[5];
  const float* root1  = (const float*)d_in[6];
  const float* bias1  = (const float*)d_in[7];
  const float* basis2 = (const float*)d_in[8];
  const float* comp2  = (const float*)d_in[9];
  const float* root2  = (const float*)d_in[10];
  const float* bias2  = (const float*)d_in[11];
  float* out = (float*)d_out;

  // workspace layout (bytes); total 120,186,880 (< 122.6 MB proven in round 2)
  char* ws = (char*)d_ws;
  unsigned* cnt      = (unsigned*)(ws);                    // 10,000,128
  unsigned* deg      = (unsigned*)(ws + 10000128);         //    200,064
  unsigned* cursor   = (unsigned*)(ws + 10200192);         //    200,064
  int* rowstart      = (int*)(ws + 10400256);              //    200,128
  uint32_t* epack    = (uint32_t*)(ws + 10600384);         //  3,200,000
  float* icl         = (float*)(ws + 13800384);            //  3,200,000
  ushort_t* Bcat     = (ushort_t*)(ws + 17000384);         //    786,432 (+pad)
  float* hxr         = (float*)(ws + 17786880);            // 102,400,000
  float* hxr2        = (float*)(ws);                       // 3.6 MB overlay (cnt dead)

  // k1, k2 = jax.random.split(jax.random.key(42)), partitionable scheme
  uint32_t k1a, k1b, k2a, k2b;
  tf2x32(0u, 42u, 0u, 0u, k1a, k1b);
  tf2x32(0u, 42u, 0u, 1u, k2a, k2b);

  hipMemsetAsync(ws, 0, 10400256, stream);  // cnt + deg + cursor

  count_k<<<(NE + 255) / 256, 256, 0, stream>>>(ei, et, cnt, deg);
  scan_k<<<1, 256, 0, stream>>>(deg, rowstart);
  fill_k<<<(NE + 255) / 256, 256, 0, stream>>>(ei, et, cnt, rowstart, cursor,
                                               epack, icl);
  bcat_k<<<(512 * FIN + 255) / 256, 256, 0, stream>>>(basis1, root1, Bcat);

  mfma_gemm_k<<<dim3((NN + 127) / 128, 4), 256, 0, stream>>>(x, Bcat, hxr, NN);

  gather1_k<<<(NN + 3) / 4, 256, 0, stream>>>(rowstart, epack, icl, comp1, hxr,
                                              bias1, k1a, k1b);

  gemm2_k<<<(NN + 3) / 4, 256, 0, stream>>>(hxr + 256, basis2, root2, hxr2);

  gather2_k<<<(NN + 255) / 256, 256, 0, stream>>>(rowstart, epack, icl, comp2,
                                                  hxr2, bias2, out, k2a, k2b);
}

// Round 4
// 453.957 us; speedup vs baseline: 8.9767x; 1.2210x over previous
//
#include <hip/hip_runtime.h>
#include <stdint.h>
#include <stddef.h>

// Problem constants (fixed by the reference)
#define NN 50000    // nodes
#define NE 800000   // edges
#define NR 50       // relations
#define FIN 768
#define HD 256
#define NC 9

typedef __bf16 bf16x8 __attribute__((ext_vector_type(8)));
typedef float f32x4 __attribute__((ext_vector_type(4)));
typedef unsigned short ushort_t;

// ---------------- Threefry-2x32-20 (JAX / Random123, partitionable) ----------------
__host__ __device__ static inline void tf2x32(uint32_t k0, uint32_t k1,
                                              uint32_t x0, uint32_t x1,
                                              uint32_t& o0, uint32_t& o1) {
  uint32_t ks2 = k0 ^ k1 ^ 0x1BD11BDAu;
  x0 += k0; x1 += k1;
#define TF_R(r) { x0 += x1; x1 = (x1 << r) | (x1 >> (32 - r)); x1 ^= x0; }
  TF_R(13) TF_R(15) TF_R(26) TF_R(6)
  x0 += k1;  x1 += ks2 + 1u;
  TF_R(17) TF_R(29) TF_R(16) TF_R(24)
  x0 += ks2; x1 += k0 + 2u;
  TF_R(13) TF_R(15) TF_R(26) TF_R(6)
  x0 += k0;  x1 += k1 + 3u;
  TF_R(17) TF_R(29) TF_R(16) TF_R(24)
  x0 += k1;  x1 += ks2 + 4u;
  TF_R(13) TF_R(15) TF_R(26) TF_R(6)
  x0 += ks2; x1 += k0 + 5u;
#undef TF_R
  o0 = x0; o1 = x1;
}

__device__ static inline float jax_unif(uint32_t ka, uint32_t kb, uint32_t i) {
  uint32_t o0, o1;
  tf2x32(ka, kb, 0u, i, o0, o1);
  uint32_t bits = o0 ^ o1;
  return __uint_as_float((bits >> 9) | 0x3f800000u) - 1.0f;
}

// dropout(p=0.4)+relu on value v at flat index i
__device__ static inline float drelu(float v, uint32_t ka, uint32_t kb, uint32_t i) {
  float r = (jax_unif(ka, kb, i) < 0.6f) ? (v * (1.0f / 0.6f)) : 0.0f;
  return fmaxf(r, 0.0f);
}

// f32 -> bf16 (round half up), packed pair / single
__device__ static inline uint32_t pk2(float lo, float hi) {
  uint32_t a = (__float_as_uint(lo) + 0x8000u) >> 16;
  uint32_t b = (__float_as_uint(hi) + 0x8000u) & 0xFFFF0000u;
  return a | b;
}
__device__ static inline ushort_t bf1(float v) {
  return (ushort_t)((__float_as_uint(v) + 0x8000u) >> 16);
}
__device__ static inline float ulo(uint32_t u) { return __uint_as_float(u << 16); }
__device__ static inline float uhi(uint32_t u) { return __uint_as_float(u & 0xFFFF0000u); }

// LDS tile byte offset for (row r, 16B-segment s), XOR-swizzled (involution)
__device__ static inline int swz(int r, int s) {
  return r * 64 + ((s ^ ((r >> 1) & 3)) << 4);
}

#define GLDS16(gp, lp) __builtin_amdgcn_global_load_lds(                        \
    (const __attribute__((address_space(1))) void*)(gp),                        \
    (__attribute__((address_space(3))) void*)(lp), 16, 0, 0)

// ---------------- graph prep ----------------

__global__ __launch_bounds__(256) void count_k(const int* __restrict__ ei,
                                               const int* __restrict__ et,
                                               unsigned* __restrict__ cnt,
                                               unsigned* __restrict__ deg) {
  int e = blockIdx.x * 256 + threadIdx.x;
  if (e >= NE) return;
  int dst = ei[NE + e];
  int t = et[e];
  atomicAdd(&cnt[(size_t)dst * NR + t], 1u);
  atomicAdd(&deg[dst], 1u);
}

__global__ __launch_bounds__(1024) void scan_k(const unsigned* __restrict__ deg,
                                               int* __restrict__ rowstart) {
  __shared__ int part[1024];
  const int CH = (NN + 1023) / 1024;  // 49
  int t = threadIdx.x;
  int lo = t * CH, hi = min(lo + CH, NN);
  int s = 0;
  for (int i = lo; i < hi; ++i) s += (int)deg[i];
  part[t] = s;
  __syncthreads();
  for (int off = 1; off < 1024; off <<= 1) {
    int v = 0;
    if (t >= off) v = part[t - off];
    __syncthreads();
    part[t] += v;
    __syncthreads();
  }
  int run = (t == 0) ? 0 : part[t - 1];
  for (int i = lo; i < hi; ++i) { rowstart[i] = run; run += (int)deg[i]; }
  if (t == 1023) rowstart[NN] = run;
}

// CSR slots: epw[slot] = { src | (t<<16), bits(1/cnt) }
__global__ __launch_bounds__(256) void fill_k(const int* __restrict__ ei,
                                              const int* __restrict__ et,
                                              const unsigned* __restrict__ cnt,
                                              const int* __restrict__ rowstart,
                                              unsigned* __restrict__ cursor,
                                              uint2* __restrict__ epw) {
  int e = blockIdx.x * 256 + threadIdx.x;
  if (e >= NE) return;
  int src = ei[e];
  int dst = ei[NE + e];
  int t = et[e];
  unsigned pos = atomicAdd(&cursor[dst], 1u);
  int slot = rowstart[dst] + (int)pos;
  float ic = 1.0f / (float)cnt[(size_t)dst * NR + t];
  epw[slot] = make_uint2((uint32_t)src | ((uint32_t)t << 16), __float_as_uint(ic));
}

// Bcat[n][k] bf16, n in [0,512): n<256 -> basis1[0][k][n], else root1[k][n-256]
__global__ __launch_bounds__(256) void bcat_k(const float* __restrict__ basis1,
                                              const float* __restrict__ root1,
                                              ushort_t* __restrict__ Bcat) {
  int i = blockIdx.x * 256 + threadIdx.x;
  if (i >= 512 * FIN) return;
  int n = i / FIN, k = i - n * FIN;
  float v = (n < HD) ? basis1[k * HD + n] : root1[k * HD + (n - HD)];
  Bcat[i] = bf1(v);
}

// ---------------- fused layer-1 GEMM: hxb[M][512](bf16) = x @ [basis1|root1] ----------------
// bf16 MFMA 16x16x32, 128x128 tile, BK=32, 4 waves (2x2), 4x4 frags/wave.
// grid (4, 391): bn tiles sharing an A-panel dispatch consecutively (A LLC reuse).
__global__ __launch_bounds__(256) void mfma_gemm_k(const float* __restrict__ A,
                                                   const ushort_t* __restrict__ Bc,
                                                   ushort_t* __restrict__ C, int M) {
  __shared__ alignas(16) unsigned char ldsA[8192];
  __shared__ alignas(16) unsigned char ldsB[8192];
  const int K = FIN;
  int bn = blockIdx.x * 128;
  int bm = blockIdx.y * 128;
  int t = threadIdx.x;
  int lane = t & 63, w = t >> 6;
  int wm = w >> 1, wn = w & 1;
  int fr = lane & 15, fs = lane >> 4;

  f32x4 acc[4][4];
#pragma unroll
  for (int m = 0; m < 4; ++m)
#pragma unroll
    for (int n = 0; n < 4; ++n) acc[m][n] = (f32x4){0.f, 0.f, 0.f, 0.f};

  int aoff[4], boff[4];
#pragma unroll
  for (int m = 0; m < 4; ++m) aoff[m] = swz(wm * 64 + m * 16 + fr, fs);
#pragma unroll
  for (int n = 0; n < 4; ++n) boff[n] = swz(wn * 64 + n * 16 + fr, fs);

  int rA = t >> 1, half = t & 1;
  const float4* gA =
      (const float4*)(A + (size_t)min(bm + rA, M - 1) * K + half * 16);

  float4 f0, f1, f2, f3;
  {
    const float4* p = gA;
    f0 = p[0]; f1 = p[1]; f2 = p[2]; f3 = p[3];
  }

  for (int k0 = 0; k0 < K; k0 += 32) {
    __syncthreads();
#pragma unroll
    for (int q = 0; q < 2; ++q) {
      int c = q * 256 + t;
      int r = c >> 2, sp = c & 3;
      int s = sp ^ ((r >> 1) & 3);
      GLDS16(Bc + (size_t)(bn + r) * K + k0 + s * 8,
             ldsB + q * 4096 + w * 1024);
    }
    uint4 c0, c1;
    c0.x = pk2(f0.x, f0.y); c0.y = pk2(f0.z, f0.w);
    c0.z = pk2(f1.x, f1.y); c0.w = pk2(f1.z, f1.w);
    c1.x = pk2(f2.x, f2.y); c1.y = pk2(f2.z, f2.w);
    c1.z = pk2(f3.x, f3.y); c1.w = pk2(f3.z, f3.w);
    *(uint4*)(ldsA + swz(rA, half * 2)) = c0;
    *(uint4*)(ldsA + swz(rA, half * 2 + 1)) = c1;
    __syncthreads();
    if (k0 + 32 < K) {
      const float4* p = gA + ((k0 + 32) >> 2);
      f0 = p[0]; f1 = p[1]; f2 = p[2]; f3 = p[3];
    }
    bf16x8 af[4], bfr[4];
#pragma unroll
    for (int m = 0; m < 4; ++m) af[m] = *(const bf16x8*)(ldsA + aoff[m]);
#pragma unroll
    for (int n = 0; n < 4; ++n) bfr[n] = *(const bf16x8*)(ldsB + boff[n]);
#pragma unroll
    for (int m = 0; m < 4; ++m)
#pragma unroll
      for (int n = 0; n < 4; ++n)
        acc[m][n] = __builtin_amdgcn_mfma_f32_16x16x32_bf16(af[m], bfr[n],
                                                            acc[m][n], 0, 0, 0);
  }

  // epilogue: C/D layout col = lane&15, row = (lane>>4)*4 + reg  [m89-verified]
#pragma unroll
  for (int m = 0; m < 4; ++m) {
    int rbase = bm + wm * 64 + m * 16 + fs * 4;
#pragma unroll
    for (int r4 = 0; r4 < 4; ++r4) {
      int row = rbase + r4;
      if (row < M) {
        ushort_t* crow = C + (size_t)row * 512 + bn + wn * 64 + fr;
#pragma unroll
        for (int n = 0; n < 4; ++n) crow[n * 16] = bf1(acc[m][n][r4]);
      }
    }
  }
}

// ---------------- aggregation / epilogues ----------------

// one wave per dst node over hxb[NN][512] bf16 (cols 0..255 = hx, 256..511 = xr);
// writes h1 (bf16) over own row's xr half.
__global__ __launch_bounds__(256) void gather1_k(const int* __restrict__ rowstart,
                                                 const uint2* __restrict__ epw,
                                                 const float* __restrict__ comp1,
                                                 ushort_t* __restrict__ hxb,
                                                 const float* __restrict__ bias1,
                                                 uint32_t ka, uint32_t kb) {
  int node = blockIdx.x * 4 + (threadIdx.x >> 6);
  int lane = threadIdx.x & 63;
  if (node >= NN) return;
  int rs = rowstart[node], re = rowstart[node + 1];
  float4 acc = make_float4(0.f, 0.f, 0.f, 0.f);
  for (int j = rs; j < re; ++j) {
    uint2 e = epw[j];
    int src = (int)(e.x & 0xFFFFu);
    float w = comp1[e.x >> 16] * __uint_as_float(e.y);
    uint2 u = *(const uint2*)(hxb + (size_t)src * 512 + lane * 4);
    acc.x += w * ulo(u.x); acc.y += w * uhi(u.x);
    acc.z += w * ulo(u.y); acc.w += w * uhi(u.y);
  }
  ushort_t* xrow = hxb + (size_t)node * 512 + 256 + lane * 4;
  uint2 xu = *(const uint2*)xrow;
  float4 b = *(const float4*)(bias1 + lane * 4);
  uint32_t base = (uint32_t)(node * HD + lane * 4);
  float ox = drelu(acc.x + ulo(xu.x) + b.x, ka, kb, base + 0);
  float oy = drelu(acc.y + uhi(xu.x) + b.y, ka, kb, base + 1);
  float oz = drelu(acc.z + ulo(xu.y) + b.z, ka, kb, base + 2);
  float ow = drelu(acc.w + uhi(xu.y) + b.w, ka, kb, base + 3);
  *(uint2*)xrow = make_uint2(pk2(ox, oy), pk2(oz, ow));
}

// layer-2 projections, thread per node: hxr2[n,0..8] = h1@basis2 ; [9..17] = h1@root2
// h1 = bf16 at hxb[n][256..511]
__global__ __launch_bounds__(256) void gemm2_k(const ushort_t* __restrict__ hxb,
                                               const float* __restrict__ basis2,
                                               const float* __restrict__ root2,
                                               float* __restrict__ hxr2) {
  __shared__ float W[256][20];  // padded stride
  int tid = threadIdx.x;
  for (int p = tid; p < 256 * 18; p += 256) {
    int k = p / 18, c = p % 18;
    W[k][c] = (c < 9) ? basis2[k * 9 + c] : root2[k * 9 + (c - 9)];
  }
  __syncthreads();
  int n = blockIdx.x * 256 + tid;
  if (n >= NN) return;
  const ushort_t* hp = hxb + (size_t)n * 512 + 256;
  float acc[18];
#pragma unroll
  for (int c = 0; c < 18; ++c) acc[c] = 0.f;
  for (int k0 = 0; k0 < 256; k0 += 8) {
    uint4 u = *(const uint4*)(hp + k0);
    float f[8];
    f[0] = ulo(u.x); f[1] = uhi(u.x); f[2] = ulo(u.y); f[3] = uhi(u.y);
    f[4] = ulo(u.z); f[5] = uhi(u.z); f[6] = ulo(u.w); f[7] = uhi(u.w);
#pragma unroll
    for (int q = 0; q < 8; ++q)
#pragma unroll
      for (int c = 0; c < 18; ++c) acc[c] += f[q] * W[k0 + q][c];
  }
  float* op = hxr2 + (size_t)n * 18;
#pragma unroll
  for (int c = 0; c < 18; ++c) op[c] = acc[c];
}

// one thread per dst node: out = relu(dropout(sum w2*hx2[src] + xr2 + b2))
__global__ __launch_bounds__(256) void gather2_k(const int* __restrict__ rowstart,
                                                 const uint2* __restrict__ epw,
                                                 const float* __restrict__ comp2,
                                                 const float* __restrict__ hxr2,
                                                 const float* __restrict__ bias2,
                                                 float* __restrict__ out,
                                                 uint32_t ka, uint32_t kb) {
  int n = blockIdx.x * 256 + threadIdx.x;
  if (n >= NN) return;
  int rs = rowstart[n], re = rowstart[n + 1];
  float acc[9];
#pragma unroll
  for (int c = 0; c < 9; ++c) acc[c] = 0.f;
  for (int j = rs; j < re; ++j) {
    uint2 e = epw[j];
    int src = (int)(e.x & 0xFFFFu);
    float w = comp2[e.x >> 16] * __uint_as_float(e.y);
    const float* hp = hxr2 + (size_t)src * 18;
#pragma unroll
    for (int c = 0; c < 9; ++c) acc[c] += w * hp[c];
  }
  const float* xp = hxr2 + (size_t)n * 18 + 9;
#pragma unroll
  for (int c = 0; c < 9; ++c) {
    float v = acc[c] + xp[c] + bias2[c];
    out[n * 9 + c] = drelu(v, ka, kb, (uint32_t)(n * 9 + c));
  }
}

// ---------------- launch ----------------
extern "C" void kernel_launch(void* const* d_in, const int* in_sizes, int n_in,
                              void* d_out, int out_size, void* d_ws, size_t ws_size,
                              hipStream_t stream) {
  (void)in_sizes; (void)n_in; (void)out_size; (void)ws_size;
  const float* x      = (const float*)d_in[0];
  const int*   ei     = (const int*)d_in[1];
  const int*   et     = (const int*)d_in[2];
  const float* basis1 = (const float*)d_in[4];
  const float* comp1  = (const float*)d_in[5];
  const float* root1  = (const float*)d_in[6];
  const float* bias1  = (const float*)d_in[7];
  const float* basis2 = (const float*)d_in[8];
  const float* comp2  = (const float*)d_in[9];
  const float* root2  = (const float*)d_in[10];
  const float* bias2  = (const float*)d_in[11];
  float* out = (float*)d_out;

  // workspace layout (bytes); total ~69 MB
  char* ws = (char*)d_ws;
  unsigned* cnt    = (unsigned*)(ws);                  // 10,000,128
  unsigned* deg    = (unsigned*)(ws + 10000128);       //    200,064
  unsigned* cursor = (unsigned*)(ws + 10200192);       //    200,064
  int* rowstart    = (int*)(ws + 10400256);            //    200,128
  uint2* epw       = (uint2*)(ws + 10600384);          //  6,400,000
  ushort_t* Bcat   = (ushort_t*)(ws + 17000384);       //    786,432 (+pad 64)
  ushort_t* hxb    = (ushort_t*)(ws + 17786880);       // 51,200,000
  float* hxr2      = (float*)(ws);                     // 3.6 MB overlay (cnt dead)

  // k1, k2 = jax.random.split(jax.random.key(42)), partitionable scheme
  uint32_t k1a, k1b, k2a, k2b;
  tf2x32(0u, 42u, 0u, 0u, k1a, k1b);
  tf2x32(0u, 42u, 0u, 1u, k2a, k2b);

  hipMemsetAsync(ws, 0, 10400256, stream);  // cnt + deg + cursor

  count_k<<<(NE + 255) / 256, 256, 0, stream>>>(ei, et, cnt, deg);
  scan_k<<<1, 1024, 0, stream>>>(deg, rowstart);
  fill_k<<<(NE + 255) / 256, 256, 0, stream>>>(ei, et, cnt, rowstart, cursor, epw);
  bcat_k<<<(512 * FIN + 255) / 256, 256, 0, stream>>>(basis1, root1, Bcat);

  mfma_gemm_k<<<dim3(4, (NN + 127) / 128), 256, 0, stream>>>(x, Bcat, hxb, NN);

  gather1_k<<<(NN + 3) / 4, 256, 0, stream>>>(rowstart, epw, comp1, hxb, bias1,
                                              k1a, k1b);

  gemm2_k<<<(NN + 255) / 256, 256, 0, stream>>>(hxb, basis2, root2, hxr2);

  gather2_k<<<(NN + 255) / 256, 256, 0, stream>>>(rowstart, epw, comp2, hxr2,
                                                  bias2, out, k2a, k2b);
}

// Round 5
// 398.932 us; speedup vs baseline: 10.2148x; 1.1379x over previous
//
#include <hip/hip_runtime.h>
#include <stdint.h>
#include <stddef.h>

// Problem constants (fixed by the reference)
#define NN 50000    // nodes
#define NE 800000   // edges
#define NR 50       // relations
#define FIN 768
#define HD 256
#define NC 9

typedef __bf16 bf16x8 __attribute__((ext_vector_type(8)));
typedef float f32x4 __attribute__((ext_vector_type(4)));
typedef unsigned short ushort_t;

// ---------------- Threefry-2x32-20 (JAX / Random123, partitionable) ----------------
__host__ __device__ static inline void tf2x32(uint32_t k0, uint32_t k1,
                                              uint32_t x0, uint32_t x1,
                                              uint32_t& o0, uint32_t& o1) {
  uint32_t ks2 = k0 ^ k1 ^ 0x1BD11BDAu;
  x0 += k0; x1 += k1;
#define TF_R(r) { x0 += x1; x1 = (x1 << r) | (x1 >> (32 - r)); x1 ^= x0; }
  TF_R(13) TF_R(15) TF_R(26) TF_R(6)
  x0 += k1;  x1 += ks2 + 1u;
  TF_R(17) TF_R(29) TF_R(16) TF_R(24)
  x0 += ks2; x1 += k0 + 2u;
  TF_R(13) TF_R(15) TF_R(26) TF_R(6)
  x0 += k0;  x1 += k1 + 3u;
  TF_R(17) TF_R(29) TF_R(16) TF_R(24)
  x0 += k1;  x1 += ks2 + 4u;
  TF_R(13) TF_R(15) TF_R(26) TF_R(6)
  x0 += ks2; x1 += k0 + 5u;
#undef TF_R
  o0 = x0; o1 = x1;
}

__device__ static inline float jax_unif(uint32_t ka, uint32_t kb, uint32_t i) {
  uint32_t o0, o1;
  tf2x32(ka, kb, 0u, i, o0, o1);
  uint32_t bits = o0 ^ o1;
  return __uint_as_float((bits >> 9) | 0x3f800000u) - 1.0f;
}

// dropout(p=0.4)+relu on value v at flat index i
__device__ static inline float drelu(float v, uint32_t ka, uint32_t kb, uint32_t i) {
  float r = (jax_unif(ka, kb, i) < 0.6f) ? (v * (1.0f / 0.6f)) : 0.0f;
  return fmaxf(r, 0.0f);
}

// f32 -> bf16 (round half up), packed pair / single
__device__ static inline uint32_t pk2(float lo, float hi) {
  uint32_t a = (__float_as_uint(lo) + 0x8000u) >> 16;
  uint32_t b = (__float_as_uint(hi) + 0x8000u) & 0xFFFF0000u;
  return a | b;
}
__device__ static inline ushort_t bf1(float v) {
  return (ushort_t)((__float_as_uint(v) + 0x8000u) >> 16);
}
__device__ static inline float ulo(uint32_t u) { return __uint_as_float(u << 16); }
__device__ static inline float uhi(uint32_t u) { return __uint_as_float(u & 0xFFFF0000u); }

// LDS tile byte offset for (row r, 16B-segment s), XOR-swizzled (involution)
__device__ static inline int swz(int r, int s) {
  return r * 64 + ((s ^ ((r >> 1) & 3)) << 4);
}

#define GLDS16(gp, lp) __builtin_amdgcn_global_load_lds(                        \
    (const __attribute__((address_space(1))) void*)(gp),                        \
    (__attribute__((address_space(3))) void*)(lp), 16, 0, 0)

// ---------------- graph prep ----------------

__global__ __launch_bounds__(256) void count_k(const int* __restrict__ ei,
                                               const int* __restrict__ et,
                                               unsigned* __restrict__ cnt,
                                               unsigned* __restrict__ deg) {
  int e = blockIdx.x * 256 + threadIdx.x;
  if (e >= NE) return;
  int dst = ei[NE + e];
  int t = et[e];
  atomicAdd(&cnt[(size_t)dst * NR + t], 1u);
  atomicAdd(&deg[dst], 1u);
}

__global__ __launch_bounds__(1024) void scan_k(const unsigned* __restrict__ deg,
                                               int* __restrict__ rowstart) {
  __shared__ int part[1024];
  const int CH = (NN + 1023) / 1024;  // 49
  int t = threadIdx.x;
  int lo = t * CH, hi = min(lo + CH, NN);
  int s = 0;
  for (int i = lo; i < hi; ++i) s += (int)deg[i];
  part[t] = s;
  __syncthreads();
  for (int off = 1; off < 1024; off <<= 1) {
    int v = 0;
    if (t >= off) v = part[t - off];
    __syncthreads();
    part[t] += v;
    __syncthreads();
  }
  int run = (t == 0) ? 0 : part[t - 1];
  for (int i = lo; i < hi; ++i) { rowstart[i] = run; run += (int)deg[i]; }
  if (t == 1023) rowstart[NN] = run;
}

// CSR slots: epw[slot] = { src | (t<<16), bits(1/cnt) }
__global__ __launch_bounds__(256) void fill_k(const int* __restrict__ ei,
                                              const int* __restrict__ et,
                                              const unsigned* __restrict__ cnt,
                                              const int* __restrict__ rowstart,
                                              unsigned* __restrict__ cursor,
                                              uint2* __restrict__ epw) {
  int e = blockIdx.x * 256 + threadIdx.x;
  if (e >= NE) return;
  int src = ei[e];
  int dst = ei[NE + e];
  int t = et[e];
  unsigned pos = atomicAdd(&cursor[dst], 1u);
  int slot = rowstart[dst] + (int)pos;
  float ic = 1.0f / (float)cnt[(size_t)dst * NR + t];
  epw[slot] = make_uint2((uint32_t)src | ((uint32_t)t << 16), __float_as_uint(ic));
}

// Bcat[n][k] bf16, n in [0,512): n<256 -> basis1[0][k][n], else root1[k][n-256]
__global__ __launch_bounds__(256) void bcat_k(const float* __restrict__ basis1,
                                              const float* __restrict__ root1,
                                              ushort_t* __restrict__ Bcat) {
  int i = blockIdx.x * 256 + threadIdx.x;
  if (i >= 512 * FIN) return;
  int n = i / FIN, k = i - n * FIN;
  float v = (n < HD) ? basis1[k * HD + n] : root1[k * HD + (n - HD)];
  Bcat[i] = bf1(v);
}

// ---------------- fused layer-1 GEMM: hxb[M][512](bf16) = x @ [basis1|root1] ----------------
// bf16 MFMA 16x16x32, 128x128 tile, BK=32, 4 waves (2x2), 4x4 frags/wave.
// XCD-pinned mapping: the 4 bn-tiles of one A-panel run consecutively on ONE XCD
// (id%8 = xcd model), so each A panel is L2-fetched once.
// Double-buffered LDS, stage(t+1)-before-compute(t), ONE barrier per K-step.
__global__ __launch_bounds__(256) void mfma_gemm_k(const float* __restrict__ A,
                                                   const ushort_t* __restrict__ Bc,
                                                   ushort_t* __restrict__ C, int M) {
  __shared__ alignas(16) unsigned char ldsA[2][8192];
  __shared__ alignas(16) unsigned char ldsB[2][8192];
  const int K = FIN;
  const int NT = K / 32;  // 24 K-steps

  int id = blockIdx.x;
  int xcd = id & 7, sq = id >> 3;
  int bm128 = xcd + 8 * (sq >> 2);
  if (bm128 >= (M + 127) / 128) return;
  int bm = bm128 * 128;
  int bn = (sq & 3) * 128;

  int t = threadIdx.x;
  int lane = t & 63, w = t >> 6;
  int wm = w >> 1, wn = w & 1;
  int fr = lane & 15, fs = lane >> 4;

  f32x4 acc[4][4];
#pragma unroll
  for (int m = 0; m < 4; ++m)
#pragma unroll
    for (int n = 0; n < 4; ++n) acc[m][n] = (f32x4){0.f, 0.f, 0.f, 0.f};

  int aoff[4], boff[4];
#pragma unroll
  for (int m = 0; m < 4; ++m) aoff[m] = swz(wm * 64 + m * 16 + fr, fs);
#pragma unroll
  for (int n = 0; n < 4; ++n) boff[n] = swz(wn * 64 + n * 16 + fr, fs);

  int rA = t >> 1, half = t & 1;
  const float4* gA =
      (const float4*)(A + (size_t)min(bm + rA, M - 1) * K + half * 16);

  float4 f0, f1, f2, f3;

#define LOAD_F(step) { const float4* p = gA + (step) * 8;                      \
    f0 = p[0]; f1 = p[1]; f2 = p[2]; f3 = p[3]; }

#define STAGE_A(bi) { uint4 c0, c1;                                            \
    c0.x = pk2(f0.x, f0.y); c0.y = pk2(f0.z, f0.w);                            \
    c0.z = pk2(f1.x, f1.y); c0.w = pk2(f1.z, f1.w);                            \
    c1.x = pk2(f2.x, f2.y); c1.y = pk2(f2.z, f2.w);                            \
    c1.z = pk2(f3.x, f3.y); c1.w = pk2(f3.z, f3.w);                            \
    *(uint4*)(ldsA[bi] + swz(rA, half * 2)) = c0;                              \
    *(uint4*)(ldsA[bi] + swz(rA, half * 2 + 1)) = c1; }

#define STAGE_B(bi, k0) _Pragma("unroll")                                      \
    for (int q = 0; q < 2; ++q) {                                              \
      int c = q * 256 + t;                                                     \
      int r = c >> 2, sp = c & 3;                                              \
      int s = sp ^ ((r >> 1) & 3);                                             \
      GLDS16(Bc + (size_t)(bn + r) * K + (k0) + s * 8,                         \
             ldsB[bi] + q * 4096 + w * 1024);                                  \
    }

  // prologue: stage step 0 into buf 0, prefetch A for step 1
  LOAD_F(0);
  STAGE_A(0);
  STAGE_B(0, 0);
  LOAD_F(1);
  __syncthreads();  // drains glds B0 + A0 ds_writes (+ the step-1 A loads)

  for (int step = 0; step < NT; ++step) {
    int cb = step & 1, nb = cb ^ 1;
    if (step + 1 < NT) {
      STAGE_A(nb);                 // consumes f (data for step+1)
      STAGE_B(nb, (step + 1) * 32);
    }
    if (step + 2 < NT) LOAD_F(step + 2);  // completes during MFMAs below
    bf16x8 af[4], bfr[4];
#pragma unroll
    for (int m = 0; m < 4; ++m) af[m] = *(const bf16x8*)(ldsA[cb] + aoff[m]);
#pragma unroll
    for (int n = 0; n < 4; ++n) bfr[n] = *(const bf16x8*)(ldsB[cb] + boff[n]);
#pragma unroll
    for (int m = 0; m < 4; ++m)
#pragma unroll
      for (int n = 0; n < 4; ++n)
        acc[m][n] = __builtin_amdgcn_mfma_f32_16x16x32_bf16(af[m], bfr[n],
                                                            acc[m][n], 0, 0, 0);
    __syncthreads();  // one barrier per step: drains stage(step+1) glds too
  }
#undef LOAD_F
#undef STAGE_A
#undef STAGE_B

  // epilogue: C/D layout col = lane&15, row = (lane>>4)*4 + reg  [m89-verified]
#pragma unroll
  for (int m = 0; m < 4; ++m) {
    int rbase = bm + wm * 64 + m * 16 + fs * 4;
#pragma unroll
    for (int r4 = 0; r4 < 4; ++r4) {
      int row = rbase + r4;
      if (row < M) {
        ushort_t* crow = C + (size_t)row * 512 + bn + wn * 64 + fr;
#pragma unroll
        for (int n = 0; n < 4; ++n) crow[n * 16] = bf1(acc[m][n][r4]);
      }
    }
  }
}

// ---------------- aggregation / epilogues ----------------

// one wave per dst node over hxb[NN][512] bf16 (cols 0..255 = hx, 256..511 = xr);
// writes h1 (bf16) over own row's xr half. comp1 in LDS; epw pipelined 1-ahead.
__global__ __launch_bounds__(256) void gather1_k(const int* __restrict__ rowstart,
                                                 const uint2* __restrict__ epw,
                                                 const float* __restrict__ comp1,
                                                 ushort_t* __restrict__ hxb,
                                                 const float* __restrict__ bias1,
                                                 uint32_t ka, uint32_t kb) {
  __shared__ float cs[NR];
  if (threadIdx.x < NR) cs[threadIdx.x] = comp1[threadIdx.x];
  __syncthreads();
  int node = blockIdx.x * 4 + (threadIdx.x >> 6);
  int lane = threadIdx.x & 63;
  if (node >= NN) return;
  int rs = rowstart[node], re = rowstart[node + 1];
  float4 acc = make_float4(0.f, 0.f, 0.f, 0.f);
  uint2 e = (rs < re) ? epw[rs] : make_uint2(0u, 0u);
  for (int j = rs; j < re; ++j) {
    uint2 cur = e;
    if (j + 1 < re) e = epw[j + 1];  // in flight during the row gather
    int src = (int)(cur.x & 0xFFFFu);
    float w = cs[cur.x >> 16] * __uint_as_float(cur.y);
    uint2 u = *(const uint2*)(hxb + (size_t)src * 512 + lane * 4);
    acc.x += w * ulo(u.x); acc.y += w * uhi(u.x);
    acc.z += w * ulo(u.y); acc.w += w * uhi(u.y);
  }
  ushort_t* xrow = hxb + (size_t)node * 512 + 256 + lane * 4;
  uint2 xu = *(const uint2*)xrow;
  float4 b = *(const float4*)(bias1 + lane * 4);
  uint32_t base = (uint32_t)(node * HD + lane * 4);
  float ox = drelu(acc.x + ulo(xu.x) + b.x, ka, kb, base + 0);
  float oy = drelu(acc.y + uhi(xu.x) + b.y, ka, kb, base + 1);
  float oz = drelu(acc.z + ulo(xu.y) + b.z, ka, kb, base + 2);
  float ow = drelu(acc.w + uhi(xu.y) + b.w, ka, kb, base + 3);
  *(uint2*)xrow = make_uint2(pk2(ox, oy), pk2(oz, ow));
}

// layer-2 projections, thread per node: hxr2[n,0..8] = h1@basis2 ; [9..17] = h1@root2
__global__ __launch_bounds__(256) void gemm2_k(const ushort_t* __restrict__ hxb,
                                               const float* __restrict__ basis2,
                                               const float* __restrict__ root2,
                                               float* __restrict__ hxr2) {
  __shared__ float W[256][20];  // padded stride
  int tid = threadIdx.x;
  for (int p = tid; p < 256 * 18; p += 256) {
    int k = p / 18, c = p % 18;
    W[k][c] = (c < 9) ? basis2[k * 9 + c] : root2[k * 9 + (c - 9)];
  }
  __syncthreads();
  int n = blockIdx.x * 256 + tid;
  if (n >= NN) return;
  const ushort_t* hp = hxb + (size_t)n * 512 + 256;
  float acc[18];
#pragma unroll
  for (int c = 0; c < 18; ++c) acc[c] = 0.f;
  for (int k0 = 0; k0 < 256; k0 += 8) {
    uint4 u = *(const uint4*)(hp + k0);
    float f[8];
    f[0] = ulo(u.x); f[1] = uhi(u.x); f[2] = ulo(u.y); f[3] = uhi(u.y);
    f[4] = ulo(u.z); f[5] = uhi(u.z); f[6] = ulo(u.w); f[7] = uhi(u.w);
#pragma unroll
    for (int q = 0; q < 8; ++q)
#pragma unroll
      for (int c = 0; c < 18; ++c) acc[c] += f[q] * W[k0 + q][c];
  }
  float* op = hxr2 + (size_t)n * 18;
#pragma unroll
  for (int c = 0; c < 18; ++c) op[c] = acc[c];
}

// one thread per dst node: out = relu(dropout(sum w2*hx2[src] + xr2 + b2))
__global__ __launch_bounds__(256) void gather2_k(const int* __restrict__ rowstart,
                                                 const uint2* __restrict__ epw,
                                                 const float* __restrict__ comp2,
                                                 const float* __restrict__ hxr2,
                                                 const float* __restrict__ bias2,
                                                 float* __restrict__ out,
                                                 uint32_t ka, uint32_t kb) {
  __shared__ float cs[NR];
  if (threadIdx.x < NR) cs[threadIdx.x] = comp2[threadIdx.x];
  __syncthreads();
  int n = blockIdx.x * 256 + threadIdx.x;
  if (n >= NN) return;
  int rs = rowstart[n], re = rowstart[n + 1];
  float acc[9];
#pragma unroll
  for (int c = 0; c < 9; ++c) acc[c] = 0.f;
  uint2 e = (rs < re) ? epw[rs] : make_uint2(0u, 0u);
  for (int j = rs; j < re; ++j) {
    uint2 cur = e;
    if (j + 1 < re) e = epw[j + 1];
    int src = (int)(cur.x & 0xFFFFu);
    float w = cs[cur.x >> 16] * __uint_as_float(cur.y);
    const float* hp = hxr2 + (size_t)src * 18;
#pragma unroll
    for (int c = 0; c < 9; ++c) acc[c] += w * hp[c];
  }
  const float* xp = hxr2 + (size_t)n * 18 + 9;
#pragma unroll
  for (int c = 0; c < 9; ++c) {
    float v = acc[c] + xp[c] + bias2[c];
    out[n * 9 + c] = drelu(v, ka, kb, (uint32_t)(n * 9 + c));
  }
}

// ---------------- launch ----------------
extern "C" void kernel_launch(void* const* d_in, const int* in_sizes, int n_in,
                              void* d_out, int out_size, void* d_ws, size_t ws_size,
                              hipStream_t stream) {
  (void)in_sizes; (void)n_in; (void)out_size; (void)ws_size;
  const float* x      = (const float*)d_in[0];
  const int*   ei     = (const int*)d_in[1];
  const int*   et     = (const int*)d_in[2];
  const float* basis1 = (const float*)d_in[4];
  const float* comp1  = (const float*)d_in[5];
  const float* root1  = (const float*)d_in[6];
  const float* bias1  = (const float*)d_in[7];
  const float* basis2 = (const float*)d_in[8];
  const float* comp2  = (const float*)d_in[9];
  const float* root2  = (const float*)d_in[10];
  const float* bias2  = (const float*)d_in[11];
  float* out = (float*)d_out;

  // workspace layout (bytes); total ~69 MB
  char* ws = (char*)d_ws;
  unsigned* cnt    = (unsigned*)(ws);                  // 10,000,128
  unsigned* deg    = (unsigned*)(ws + 10000128);       //    200,064
  unsigned* cursor = (unsigned*)(ws + 10200192);       //    200,064
  int* rowstart    = (int*)(ws + 10400256);            //    200,128
  uint2* epw       = (uint2*)(ws + 10600384);          //  6,400,000
  ushort_t* Bcat   = (ushort_t*)(ws + 17000384);       //    786,432 (+pad 64)
  ushort_t* hxb    = (ushort_t*)(ws + 17786880);       // 51,200,000
  float* hxr2      = (float*)(ws);                     // 3.6 MB overlay (cnt dead)

  // k1, k2 = jax.random.split(jax.random.key(42)), partitionable scheme
  uint32_t k1a, k1b, k2a, k2b;
  tf2x32(0u, 42u, 0u, 0u, k1a, k1b);
  tf2x32(0u, 42u, 0u, 1u, k2a, k2b);

  hipMemsetAsync(ws, 0, 10400256, stream);  // cnt + deg + cursor

  count_k<<<(NE + 255) / 256, 256, 0, stream>>>(ei, et, cnt, deg);
  scan_k<<<1, 1024, 0, stream>>>(deg, rowstart);
  fill_k<<<(NE + 255) / 256, 256, 0, stream>>>(ei, et, cnt, rowstart, cursor, epw);
  bcat_k<<<(512 * FIN + 255) / 256, 256, 0, stream>>>(basis1, root1, Bcat);

  // 1568 = 8 XCDs x 196 seq slots; 4 blocks idle (bm128 == 391 guard)
  mfma_gemm_k<<<1568, 256, 0, stream>>>(x, Bcat, hxb, NN);

  gather1_k<<<(NN + 3) / 4, 256, 0, stream>>>(rowstart, epw, comp1, hxb, bias1,
                                              k1a, k1b);

  gemm2_k<<<(NN + 255) / 256, 256, 0, stream>>>(hxb, basis2, root2, hxr2);

  gather2_k<<<(NN + 255) / 256, 256, 0, stream>>>(rowstart, epw, comp2, hxr2,
                                                  bias2, out, k2a, k2b);
}